// Round 3
// baseline (183.969 us; speedup 1.0000x reference)
//
#include <hip/hip_runtime.h>
#include <math.h>

namespace {

constexpr float kInvTau = 10.0f;      // 1 / 0.1
constexpr int   kBlock  = 256;
constexpr int   kGridH  = 2048;       // histogram pass blocks
constexpr int   kGridF  = 128;        // type-space reduce blocks
constexpr float kNegBig = -1e30f;     // -inf surrogate

typedef int v4i __attribute__((ext_vector_type(4)));

// merge two online-softmax states (m, s, t)
__device__ __forceinline__ void merge_state(float& m, float& s, float& t,
                                            float m2, float s2, float t2) {
    float nm = fmaxf(m, m2);
    float r1 = __expf(m  - nm);
    float r2 = __expf(m2 - nm);
    s = s * r1 + s2 * r2;
    t = t * r1 + t2 * r2;
    m = nm;
}

// wave(64) + block reduction of (m,s,t); result valid in thread 0
__device__ __forceinline__ void block_reduce(float& m, float& s, float& t) {
    #pragma unroll
    for (int off = 1; off < 64; off <<= 1) {
        float m2 = __shfl_xor(m, off);
        float s2 = __shfl_xor(s, off);
        float t2 = __shfl_xor(t, off);
        merge_state(m, s, t, m2, s2, t2);
    }
    __shared__ float sm[4], ss[4], st[4];
    int lane = threadIdx.x & 63;
    int wave = threadIdx.x >> 6;
    if (lane == 0) { sm[wave] = m; ss[wave] = s; st[wave] = t; }
    __syncthreads();
    if (threadIdx.x == 0) {
        int nw = blockDim.x >> 6;
        for (int i = 1; i < nw; ++i)
            merge_state(m, s, t, sm[i], ss[i], st[i]);
    }
}

// ---------- kernel A: per-type projection + sigmoid + zero hist ---------
__global__ void prep_kernel(const float* __restrict__ table,
                            const float* __restrict__ w,
                            const float* __restrict__ b,
                            const float* __restrict__ cl,
                            float2* __restrict__ pc,
                            unsigned* __restrict__ hist,
                            unsigned* __restrict__ ticket, int T) {
    int t = blockIdx.x * blockDim.x + threadIdx.x;
    if (t == 0) *ticket = 0;
    if (t >= T) return;
    const float4* row = reinterpret_cast<const float4*>(table) + (size_t)t * 4;
    const float4* wv  = reinterpret_cast<const float4*>(w);
    float4 r0 = row[0], r1 = row[1], r2 = row[2], r3 = row[3];
    float4 w0 = wv[0],  w1 = wv[1],  w2 = wv[2],  w3 = wv[3];
    float dot = r0.x*w0.x + r0.y*w0.y + r0.z*w0.z + r0.w*w0.w
              + r1.x*w1.x + r1.y*w1.y + r1.z*w1.z + r1.w*w1.w
              + r2.x*w2.x + r2.y*w2.y + r2.z*w2.z + r2.w*w2.w
              + r3.x*w3.x + r3.y*w3.y + r3.z*w3.z + r3.w*w3.w;
    float p = (dot + b[0]) * kInvTau;
    float c = 1.0f / (1.0f + __expf(-cl[t]));
    pc[t]   = make_float2(p, c);
    hist[t] = 0u;
}

// ---------- kernel B: histogram of the trace (fire-and-forget) ----------
__global__ __launch_bounds__(kBlock)
void hist_kernel(const int* __restrict__ trace, int S,
                 unsigned* __restrict__ hist) {
    int tid    = blockIdx.x * blockDim.x + threadIdx.x;
    int stride = gridDim.x * blockDim.x;
    const v4i* trace4 = reinterpret_cast<const v4i*>(trace);
    int S4 = S >> 2;
    for (int i = tid; i < S4; i += stride) {
        v4i v = __builtin_nontemporal_load(&trace4[i]);
        atomicAdd(&hist[v.x], 1u);
        atomicAdd(&hist[v.y], 1u);
        atomicAdd(&hist[v.z], 1u);
        atomicAdd(&hist[v.w], 1u);
    }
    for (int i = (S4 << 2) + tid; i < S; i += stride)
        atomicAdd(&hist[trace[i]], 1u);
}

// ---------- kernel C: type-space softmax reduce + fused finalize --------
__global__ __launch_bounds__(kBlock)
void reduce_kernel(const float2* __restrict__ pc,
                   const unsigned* __restrict__ hist, int T,
                   float* __restrict__ blkm, float* __restrict__ blks,
                   float* __restrict__ blkt,
                   unsigned* __restrict__ ticket,
                   const int* __restrict__ is_crash,
                   float* __restrict__ out) {
    float m = kNegBig, s = 0.f, tt = 0.f;
    int tid    = blockIdx.x * blockDim.x + threadIdx.x;
    int stride = gridDim.x * blockDim.x;
    for (int t = tid; t < T; t += stride) {
        unsigned cnt = hist[t];
        if (cnt == 0u) continue;
        float2 a = pc[t];
        if (a.x > m) { float r = __expf(m - a.x); s *= r; tt *= r; m = a.x; }
        float e = (float)cnt * __expf(a.x - m);
        s += e; tt += e * a.y;
    }
    block_reduce(m, s, tt);

    __shared__ int last;
    if (threadIdx.x == 0) {
        // publish this block's triple coherently across XCDs
        __hip_atomic_store(&blkm[blockIdx.x], m,  __ATOMIC_RELAXED, __HIP_MEMORY_SCOPE_AGENT);
        __hip_atomic_store(&blks[blockIdx.x], s,  __ATOMIC_RELAXED, __HIP_MEMORY_SCOPE_AGENT);
        __hip_atomic_store(&blkt[blockIdx.x], tt, __ATOMIC_RELAXED, __HIP_MEMORY_SCOPE_AGENT);
        __threadfence();                      // release
        unsigned r = atomicAdd(ticket, 1u);   // device-scope by default
        last = (r == (unsigned)(gridDim.x - 1)) ? 1 : 0;
    }
    __syncthreads();
    if (!last) return;

    __threadfence();                          // acquire side
    float m2 = kNegBig, s2 = 0.f, t2 = 0.f;
    for (int i = threadIdx.x; i < gridDim.x; i += blockDim.x) {
        float bm = __hip_atomic_load(&blkm[i], __ATOMIC_RELAXED, __HIP_MEMORY_SCOPE_AGENT);
        float bs = __hip_atomic_load(&blks[i], __ATOMIC_RELAXED, __HIP_MEMORY_SCOPE_AGENT);
        float bt = __hip_atomic_load(&blkt[i], __ATOMIC_RELAXED, __HIP_MEMORY_SCOPE_AGENT);
        merge_state(m2, s2, t2, bm, bs, bt);
    }
    block_reduce(m2, s2, t2);
    if (threadIdx.x == 0) {
        float explained = (s2 > 0.f) ? (t2 / s2) : 0.f;
        explained = fminf(fmaxf(explained, 0.f), 1.f);
        float contradiction = (is_crash[0] > 0)
            ? fmaxf(1.0f - explained, 0.f)
            : fmaxf(explained, 0.f);
        out[0] = contradiction;
    }
}

} // namespace

extern "C" void kernel_launch(void* const* d_in, const int* in_sizes, int n_in,
                              void* d_out, int out_size, void* d_ws, size_t ws_size,
                              hipStream_t stream) {
    const int*   trace = (const int*)  d_in[0];
    const int*   crash = (const int*)  d_in[1];
    const float* table = (const float*)d_in[2];
    const float* w     = (const float*)d_in[3];
    const float* b     = (const float*)d_in[4];
    const float* cl    = (const float*)d_in[5];
    float*       out   = (float*)d_out;

    const int S = in_sizes[0];
    const int T = in_sizes[5];

    // ws layout: [ float2 pc[T] | u32 hist[T] | blkm/blks/blkt[kGridF] | ticket ]
    char* p = (char*)d_ws;
    float2*   pc     = (float2*)p;            p += (size_t)T * sizeof(float2);
    unsigned* hist   = (unsigned*)p;          p += (size_t)T * sizeof(unsigned);
    float*    blkm   = (float*)p;             p += kGridF * sizeof(float);
    float*    blks   = (float*)p;             p += kGridF * sizeof(float);
    float*    blkt   = (float*)p;             p += kGridF * sizeof(float);
    unsigned* ticket = (unsigned*)p;

    int gridA = (T + kBlock - 1) / kBlock;
    prep_kernel<<<gridA, kBlock, 0, stream>>>(table, w, b, cl, pc, hist, ticket, T);
    hist_kernel<<<kGridH, kBlock, 0, stream>>>(trace, S, hist);
    reduce_kernel<<<kGridF, kBlock, 0, stream>>>(pc, hist, T, blkm, blks, blkt,
                                                 ticket, crash, out);
}

// Round 4
// 40.857 us; speedup vs baseline: 4.5028x; 4.5028x over previous
//
#include <hip/hip_runtime.h>
#include <math.h>

namespace {

constexpr float kInvTau = 10.0f;      // 1 / 0.1
constexpr int   kBlock  = 256;
constexpr int   kGridH  = 2048;       // gather-pass blocks

typedef int v4i __attribute__((ext_vector_type(4)));

// order-preserving float<->uint mapping for atomicMax on floats
__device__ __forceinline__ unsigned ord_of(float f) {
    unsigned b = __float_as_uint(f);
    return (b & 0x80000000u) ? ~b : (b | 0x80000000u);
}
__device__ __forceinline__ float float_of_ord(unsigned o) {
    unsigned b = (o & 0x80000000u) ? (o ^ 0x80000000u) : ~o;
    return __uint_as_float(b);
}

// ---------- kernel A: per-type projection + sigmoid + global max --------
__global__ __launch_bounds__(kBlock)
void prep_kernel(const float* __restrict__ table,
                 const float* __restrict__ w,
                 const float* __restrict__ b,
                 const float* __restrict__ cl,
                 float2* __restrict__ pc,
                 unsigned* __restrict__ maxo, int T) {
    int t = blockIdx.x * blockDim.x + threadIdx.x;
    float p = -1e30f;
    if (t < T) {
        const float4* row = reinterpret_cast<const float4*>(table) + (size_t)t * 4;
        const float4* wv  = reinterpret_cast<const float4*>(w);
        float4 r0 = row[0], r1 = row[1], r2 = row[2], r3 = row[3];
        float4 w0 = wv[0],  w1 = wv[1],  w2 = wv[2],  w3 = wv[3];
        float dot = r0.x*w0.x + r0.y*w0.y + r0.z*w0.z + r0.w*w0.w
                  + r1.x*w1.x + r1.y*w1.y + r1.z*w1.z + r1.w*w1.w
                  + r2.x*w2.x + r2.y*w2.y + r2.z*w2.z + r2.w*w2.w
                  + r3.x*w3.x + r3.y*w3.y + r3.z*w3.z + r3.w*w3.w;
        p = (dot + b[0]) * kInvTau;
        float c = 1.0f / (1.0f + __expf(-cl[t]));
        pc[t] = make_float2(p, c);
    }
    // block max of p (all threads participate in shuffles)
    float pm = p;
    #pragma unroll
    for (int off = 1; off < 64; off <<= 1)
        pm = fmaxf(pm, __shfl_xor(pm, off));
    __shared__ float wm[4];
    int lane = threadIdx.x & 63, wave = threadIdx.x >> 6;
    if (lane == 0) wm[wave] = pm;
    __syncthreads();
    if (threadIdx.x == 0) {
        float bm = fmaxf(fmaxf(wm[0], wm[1]), fmaxf(wm[2], wm[3]));
        atomicMax(maxo, ord_of(bm));   // device-scope, one per block
    }
}

// ---------- kernel B: g[t] = (exp(p-M), exp(p-M)*c) ---------------------
__global__ __launch_bounds__(kBlock)
void ebgen_kernel(const float2* __restrict__ pc,
                  const unsigned* __restrict__ maxo,
                  float2* __restrict__ g, int T) {
    int t = blockIdx.x * blockDim.x + threadIdx.x;
    if (t >= T) return;
    float M = float_of_ord(*maxo);
    float2 a = pc[t];
    float eb = __expf(a.x - M);
    g[t] = make_float2(eb, eb * a.y);
}

// ---------- kernel C: pure gather-accumulate over the trace -------------
__global__ __launch_bounds__(kBlock)
void pass_kernel(const int* __restrict__ trace, int S,
                 const float2* __restrict__ g,
                 float2* __restrict__ blk) {
    float s0 = 0.f, s1 = 0.f, t0 = 0.f, t1 = 0.f;
    int tid    = blockIdx.x * blockDim.x + threadIdx.x;
    int stride = gridDim.x * blockDim.x;
    const v4i* trace4 = reinterpret_cast<const v4i*>(trace);
    int S4 = S >> 2;
    #pragma unroll 2
    for (int i = tid; i < S4; i += stride) {
        v4i v = __builtin_nontemporal_load(&trace4[i]);
        float2 a0 = g[v.x], a1 = g[v.y], a2 = g[v.z], a3 = g[v.w];
        s0 += a0.x + a2.x;  t0 += a0.y + a2.y;
        s1 += a1.x + a3.x;  t1 += a1.y + a3.y;
    }
    for (int i = (S4 << 2) + tid; i < S; i += stride) {
        float2 a = g[trace[i]];
        s0 += a.x; t0 += a.y;
    }
    float s = s0 + s1, t = t0 + t1;
    // block sum
    #pragma unroll
    for (int off = 1; off < 64; off <<= 1) {
        s += __shfl_xor(s, off);
        t += __shfl_xor(t, off);
    }
    __shared__ float ws_[4], wt_[4];
    int lane = threadIdx.x & 63, wave = threadIdx.x >> 6;
    if (lane == 0) { ws_[wave] = s; wt_[wave] = t; }
    __syncthreads();
    if (threadIdx.x == 0) {
        s = ws_[0] + ws_[1] + ws_[2] + ws_[3];
        t = wt_[0] + wt_[1] + wt_[2] + wt_[3];
        blk[blockIdx.x] = make_float2(s, t);
    }
}

// ---------- kernel D: finalize ------------------------------------------
__global__ __launch_bounds__(kBlock)
void final_kernel(const float2* __restrict__ blk, int nblk,
                  const int* __restrict__ is_crash,
                  float* __restrict__ out) {
    float s = 0.f, t = 0.f;
    for (int i = threadIdx.x; i < nblk; i += blockDim.x) {
        float2 b = blk[i];
        s += b.x; t += b.y;
    }
    #pragma unroll
    for (int off = 1; off < 64; off <<= 1) {
        s += __shfl_xor(s, off);
        t += __shfl_xor(t, off);
    }
    __shared__ float ws_[4], wt_[4];
    int lane = threadIdx.x & 63, wave = threadIdx.x >> 6;
    if (lane == 0) { ws_[wave] = s; wt_[wave] = t; }
    __syncthreads();
    if (threadIdx.x == 0) {
        s = ws_[0] + ws_[1] + ws_[2] + ws_[3];
        t = wt_[0] + wt_[1] + wt_[2] + wt_[3];
        float explained = (s > 0.f) ? (t / s) : 0.f;
        explained = fminf(fmaxf(explained, 0.f), 1.f);
        float contradiction = (is_crash[0] > 0)
            ? fmaxf(1.0f - explained, 0.f)
            : fmaxf(explained, 0.f);
        out[0] = contradiction;
    }
}

} // namespace

extern "C" void kernel_launch(void* const* d_in, const int* in_sizes, int n_in,
                              void* d_out, int out_size, void* d_ws, size_t ws_size,
                              hipStream_t stream) {
    const int*   trace = (const int*)  d_in[0];
    const int*   crash = (const int*)  d_in[1];
    const float* table = (const float*)d_in[2];
    const float* w     = (const float*)d_in[3];
    const float* b     = (const float*)d_in[4];
    const float* cl    = (const float*)d_in[5];
    float*       out   = (float*)d_out;

    const int S = in_sizes[0];
    const int T = in_sizes[5];

    // ws layout: [ float2 pc[T] | float2 g[T] | float2 blk[kGridH] | u32 maxo ]
    char* p = (char*)d_ws;
    float2*   pc   = (float2*)p;   p += (size_t)T * sizeof(float2);
    float2*   g    = (float2*)p;   p += (size_t)T * sizeof(float2);
    float2*   blk  = (float2*)p;   p += (size_t)kGridH * sizeof(float2);
    unsigned* maxo = (unsigned*)p;

    // ord(0) maps to NaN-negative => smaller than ord of any real float
    hipMemsetAsync(maxo, 0, sizeof(unsigned), stream);

    int gridT = (T + kBlock - 1) / kBlock;
    prep_kernel <<<gridT, kBlock, 0, stream>>>(table, w, b, cl, pc, maxo, T);
    ebgen_kernel<<<gridT, kBlock, 0, stream>>>(pc, maxo, g, T);
    pass_kernel <<<kGridH, kBlock, 0, stream>>>(trace, S, g, blk);
    final_kernel<<<1, kBlock, 0, stream>>>(blk, kGridH, crash, out);
}